// Round 5
// baseline (146.542 us; speedup 1.0000x reference)
//
#include <hip/hip_runtime.h>
#include <hip/hip_bf16.h>

#define NB 8
#define NS 2048
#define NE 1024
#define ND 64

typedef __attribute__((ext_vector_type(8))) short bf16x8;
typedef __attribute__((ext_vector_type(4))) float f32x4;
typedef unsigned short u16;
typedef unsigned long long u64;

#define MFMA(a, b, c) __builtin_amdgcn_mfma_f32_16x16x32_bf16(a, b, c, 0, 0, 0)
// raw barrier keeping N vector-mem ops in flight (each wave issues exactly 2
// global_load_lds per chunk; KEEPB(4) = drain current chunk, keep next 2 chunks)
#define KEEPB(n) asm volatile("s_waitcnt vmcnt(" #n ")\n\ts_barrier" ::: "memory")

__device__ __forceinline__ u16 f2bf(float f) {
  unsigned int u = __float_as_uint(f);
  u += 0x7fffu + ((u >> 16) & 1u);  // RNE; inputs finite
  return (u16)(u >> 16);
}
__device__ __forceinline__ unsigned cvt2(float a, float b) {  // pack 2 bf16
  __hip_bfloat162 h = __float22bfloat162_rn(float2{a, b});
  return *(unsigned*)&h;
}

// async copy: each lane 16 B; LDS dst = wave-uniform base + lane*16
__device__ __forceinline__ void alds16(const void* g, void* l) {
  __builtin_amdgcn_global_load_lds(
      (const __attribute__((address_space(1))) unsigned int*)g,
      (__attribute__((address_space(3))) unsigned int*)l, 16, 0, 0);
}

// K0: Wcat3 = bf16 W concat [q|k|v], 32-k-chunk-major PLAIN layout:
// 16-B unit d = c*768 + n*4 + v  ->  row n, k = c*32 + v*8.
__global__ void k0_prep(const float* __restrict__ Wq, const float* __restrict__ bq,
                        const float* __restrict__ Wk, const float* __restrict__ bk,
                        const float* __restrict__ Wv, const float* __restrict__ bv,
                        u16* __restrict__ Wcat3, float* __restrict__ bcat,
                        float* __restrict__ vmean) {
  int d = blockIdx.x * 256 + threadIdx.x;  // 24576 units
  int c = d / 768;
  int rem = d - c * 768;
  int n = rem >> 2;
  int v = rem & 3;
  const float* src = (n < 64) ? (Wq + n * NE) : (n < 128) ? (Wk + (n - 64) * NE)
                                                          : (Wv + (n - 128) * NE);
  const float* sp = src + c * 32 + v * 8;
  float4 a = *(const float4*)sp;
  float4 b = *(const float4*)(sp + 4);
  bf16x8 o;
  o[0] = (short)f2bf(a.x); o[1] = (short)f2bf(a.y);
  o[2] = (short)f2bf(a.z); o[3] = (short)f2bf(a.w);
  o[4] = (short)f2bf(b.x); o[5] = (short)f2bf(b.y);
  o[6] = (short)f2bf(b.z); o[7] = (short)f2bf(b.w);
  *(bf16x8*)&Wcat3[(size_t)d * 8] = o;
  if (blockIdx.x == 0) {
    int t = threadIdx.x;
    if (t < 192) bcat[t] = (t < 64) ? bq[t] : (t < 128) ? bk[t - 64] : bv[t - 128];
    vmean[t] = 0.f;
    vmean[t + 256] = 0.f;
  }
}

// K1: [16384,192] = x*W^T + b. 512 blocks x 512 thr (8 waves; wave = 16 r x 48 c).
// 32 k-chunks, QUAD-buffered async staging (waves 0-1 stage A, 2-7 stage B; 2
// global_load_lds per wave per chunk), raw s_waitcnt vmcnt(4)+s_barrier keeps 2
// future chunks in flight across the barrier (never drains to 0).
// A staged raw f32 (slot q' holds chunk q'^(row&7)); B slot v' holds v'^((n^(n>>2))&3)
// -> both frag-read patterns 2-way bank aliasing = free.
// q output pre-scaled by 0.125 (attention scale folded in). vmean accumulated here.
__global__ __launch_bounds__(512) void k1_qkv(
    const float* __restrict__ x, const u16* __restrict__ Wcat3,
    const float* __restrict__ bcat, u16* __restrict__ qb,
    u16* __restrict__ kbf2, u16* __restrict__ vtb2, float* __restrict__ vmean) {
  __shared__ float axs[4][1024];  // 16 KB  (32 rows x 32 f32 per buf)
  __shared__ u16 bsb[4][6144];    // 48 KB  (192 n x 32 k per buf)
  const int t = threadIdx.x;
  const int m0 = blockIdx.x * 32;
  const int batch = m0 >> 11;
  const int sl = m0 & (NS - 1);
  const int w = t >> 6;
  const int l = t & 63;
  const int ln = l & 15;
  const int qd = l >> 4;
  const int rg = w & 1;
  const int cg = w >> 1;

  f32x4 zf = {0.f, 0.f, 0.f, 0.f};
  f32x4 acc[3] = {zf, zf, zf};

  auto stage = [&](int c, int buf) {
    if (w < 2) {  // A: 2 instrs x 64 lanes x 16 B = 2 KB of the 4 KB chunk per wave
      #pragma unroll
      for (int i = 0; i < 2; ++i) {
        int un = w * 128 + i * 64 + l;
        int row = un >> 3;
        int q = (un & 7) ^ (row & 7);
        alds16(x + (size_t)(m0 + row) * NE + c * 32 + q * 4,
               &axs[buf][(w * 128 + i * 64) * 4]);
      }
    } else {      // B: 6 waves x 2 instrs = 12 KB chunk
      #pragma unroll
      for (int i = 0; i < 2; ++i) {
        int ub = (w - 2) * 128 + i * 64 + l;
        int n = ub >> 2;
        int v = (ub & 3) ^ ((n ^ (n >> 2)) & 3);
        alds16(Wcat3 + (size_t)c * 6144 + n * 32 + v * 8,
               &bsb[buf][((w - 2) * 128 + i * 64) * 8]);
      }
    }
  };

  auto comp = [&](int buf) {
    const int arow = rg * 16 + ln;
    const int s = arow & 7;
    float4 fa = *(const float4*)&axs[buf][arow * 32 + (((qd * 2) ^ s) << 2)];
    float4 fb = *(const float4*)&axs[buf][arow * 32 + (((qd * 2 + 1) ^ s) << 2)];
    union { bf16x8 v; unsigned u[4]; } A;
    A.u[0] = cvt2(fa.x, fa.y); A.u[1] = cvt2(fa.z, fa.w);
    A.u[2] = cvt2(fb.x, fb.y); A.u[3] = cvt2(fb.z, fb.w);
    #pragma unroll
    for (int nj = 0; nj < 3; ++nj) {
      int n = cg * 48 + nj * 16 + ln;
      int sw = (n ^ (n >> 2)) & 3;
      bf16x8 bb = *(const bf16x8*)&bsb[buf][n * 32 + ((qd ^ sw) << 3)];
      acc[nj] = MFMA(A.v, bb, acc[nj]);
    }
  };

  stage(0, 0);
  stage(1, 1);
  stage(2, 2);
  for (int c = 0; c < 29; ++c) {
    KEEPB(4);               // drain chunk c (this wave's oldest 2), keep c+1,c+2
    stage(c + 3, (c + 3) & 3);
    comp(c & 3);
  }
  KEEPB(4); comp(1);  // c=29: outstanding 29,30,31 -> keep 4 drains 29
  KEEPB(2); comp(2);  // c=30
  KEEPB(0); comp(3);  // c=31

  // C/D: col = lane&15 (n), row = quad*4 + reg (m)
  const float QS = 0.125f;  // attention scale folded into q
  #pragma unroll
  for (int nj = 0; nj < 3; ++nj) {
    int n = cg * 48 + nj * 16 + ln;
    float bias = bcat[n];
    int jbase = sl + rg * 16 + qd * 4;
    if (n < 64) {
      #pragma unroll
      for (int r = 0; r < 4; ++r)
        qb[((size_t)batch * NS + jbase + r) * ND + n] = f2bf((acc[nj][r] + bias) * QS);
    } else if (n < 128) {
      int d = n - 64;
      #pragma unroll
      for (int r = 0; r < 4; ++r) {
        int j = jbase + r;
        int pos = (((d >> 3) ^ (j & 7)) << 3) + (d & 7);
        kbf2[((size_t)batch * NS + j) * ND + pos] = f2bf(acc[nj][r] + bias);
      }
    } else {
      int d = n - 128;
      int off = (jbase & ~63) + (((((jbase >> 5) & 1) ^ ((d >> 2) & 1))) << 5) +
                (((((jbase >> 3) & 3) ^ (d & 3))) << 3) + (jbase & 7);
      ushort4 sv;
      sv.x = f2bf(acc[nj][0] + bias); sv.y = f2bf(acc[nj][1] + bias);
      sv.z = f2bf(acc[nj][2] + bias); sv.w = f2bf(acc[nj][3] + bias);
      *(ushort4*)&vtb2[((size_t)batch * ND + d) * NS + off] = sv;
      // vmean partial: 16 rows of column d from this wave
      float psum = acc[nj][0] + acc[nj][1] + acc[nj][2] + acc[nj][3] + 4.f * bias;
      psum += __shfl_xor(psum, 16);
      psum += __shfl_xor(psum, 32);
      if (l < 16) atomicAdd(&vmean[batch * ND + d], psum * (1.f / 2048.f));
    }
  }
}

// K3: MFMA flash attention (no online max: |s| <~ 4, exp fp32-safe, shift-invariant).
// 512 blocks x 512 thr (8 waves): wave = rg (16 rows) x jg (32 j of 128-j chunk).
// Tile pairing (heavy,light) interleaved for CU balance. it=0 peeled (only causal
// iteration). q arrives pre-scaled by 1/8. Async dbuf staging, 1 barrier/iter.
__global__ __launch_bounds__(512) void k3_attn(
    const u16* __restrict__ qb, const u16* __restrict__ kbf2,
    const u16* __restrict__ vtb2, const int* __restrict__ mask,
    const float* __restrict__ vmean, float* __restrict__ out) {
  __shared__ u16 ks[2][128 * 64];  // 16 KB each
  __shared__ u16 vs[2][64 * 128];  // 16 KB each (V^T rows d, 128 j)
  __shared__ union {
    u16 ps[8][16 * 40];                                       // per-wave P round trip
    struct { float mb[2][16][68]; float mlb[2][16][16]; } m;  // merge (end)
  } ub;

  const int g = blockIdx.x;
  const int b = g & 7;
  const int uu = g >> 3;
  const int tile = (uu & 1) ? (63 - (uu >> 1)) : (uu >> 1);  // heavy/light pairs
  const int i0 = tile * 32;
  const int j0f = i0 & ~127;
  const int np = (NS - j0f) >> 7;
  const int t = threadIdx.x;
  const int w = t >> 6;
  const int l = t & 63;
  const int ln = l & 15;
  const int qd = l >> 4;
  const int rg = w & 1;
  const int jg = w >> 1;

  const u16* qp = qb + ((size_t)b * NS + i0 + rg * 16 + ln) * ND + qd * 8;
  bf16x8 aq0 = *(const bf16x8*)qp;
  bf16x8 aq1 = *(const bf16x8*)(qp + 32);

  const u16* kB = kbf2 + (size_t)b * NS * ND;
  const u16* vB = vtb2 + (size_t)b * ND * NS;

  auto stage = [&](int it, int buf) {
    int j0 = j0f + it * 128;
    #pragma unroll
    for (int i = 0; i < 2; ++i) {
      int jl = w * 16 + i * 8;
      alds16(kB + (size_t)(j0 + jl) * ND + l * 8, &ks[buf][jl * 64]);
      int du = w * 2 + i;
      alds16(vB + (size_t)(du * 4 + (l >> 4)) * NS + j0 + (l & 15) * 8,
             &vs[buf][du * 512]);
    }
  };

  f32x4 zf = {0.f, 0.f, 0.f, 0.f};
  f32x4 od[4] = {zf, zf, zf, zf};
  float ls[4] = {0.f, 0.f, 0.f, 0.f};
  const int pvunit = (jg >> 1) * 8 + (((jg & 1) ^ ((ln >> 2) & 1)) << 2) + (qd ^ (ln & 3));

  stage(0, 0);
  int mval = mask[b * NS + j0f + jg * 32 + (l & 31)];

  auto body = [&](int it, bool causal) {
    u64 mv = __ballot(mval != 0);  // bits 0..31 = this wave's j window
    __syncthreads();               // drains buf[it&1] asyncs; prior compute done
    if (it + 1 < np) {
      stage(it + 1, (it + 1) & 1);
      mval = mask[b * NS + j0f + (it + 1) * 128 + jg * 32 + (l & 31)];
    }
    const int buf = it & 1;
    const int jb = j0f + it * 128 + jg * 32;

    f32x4 sc[2] = {zf, zf};
    #pragma unroll
    for (int f = 0; f < 2; ++f) {
      const u16* kr = &ks[buf][(jg * 32 + f * 16 + ln) * 64];
      bf16x8 b0 = *(const bf16x8*)&kr[((qd ^ (ln & 7)) * 8)];
      bf16x8 b1 = *(const bf16x8*)&kr[(((4 + qd) ^ (ln & 7)) * 8)];
      sc[f] = MFMA(aq0, b0, sc[f]);
      sc[f] = MFMA(aq1, b1, sc[f]);
    }
    #pragma unroll
    for (int r = 0; r < 4; ++r) {
      const int i = i0 + rg * 16 + qd * 4 + r;
      #pragma unroll
      for (int f = 0; f < 2; ++f) {
        int jl = f * 16 + ln;
        bool ok = (((mv >> jl) & 1ull) != 0) && (!causal || (jb + jl >= i));
        float p = ok ? __expf(sc[f][r]) : 0.f;  // q pre-scaled by 1/8
        ls[r] += p;
        ub.ps[w][(qd * 4 + r) * 40 + jl] = f2bf(p);
      }
    }
    // P (C-layout) -> A-frag via same-wave LDS round trip; PV (K=32)
    bf16x8 pa = *(const bf16x8*)&ub.ps[w][ln * 40 + qd * 8];
    #pragma unroll
    for (int gx = 0; gx < 4; ++gx) {
      bf16x8 bv = *(const bf16x8*)&vs[buf][(gx * 16 + ln) * 128 + pvunit * 8];
      od[gx] = MFMA(pa, bv, od[gx]);
    }
  };

  body(0, true);  // only iteration with j < i cases
  for (int it = 1; it < np; ++it) body(it, false);

  __syncthreads();  // all waves done with ub.ps before merge reuses the union
  #pragma unroll 1
  for (int s = 3; s >= 1; --s) {  // additive merge: jg s -> s-1
    if (jg == s) {
      #pragma unroll
      for (int r = 0; r < 4; ++r) {
        int row = qd * 4 + r;
        #pragma unroll
        for (int gx = 0; gx < 4; ++gx) ub.m.mb[rg][row][gx * 16 + ln] = od[gx][r];
        ub.m.mlb[rg][row][ln] = ls[r];
      }
    }
    __syncthreads();
    if (jg == s - 1) {
      #pragma unroll
      for (int r = 0; r < 4; ++r) {
        int row = qd * 4 + r;
        #pragma unroll
        for (int gx = 0; gx < 4; ++gx) od[gx][r] += ub.m.mb[rg][row][gx * 16 + ln];
        ls[r] += ub.m.mlb[rg][row][ln];
      }
    }
    __syncthreads();
  }

  if (jg == 0) {
    #pragma unroll
    for (int r = 0; r < 4; ++r) {
      #pragma unroll
      for (int o = 1; o < 16; o <<= 1) ls[r] += __shfl_xor(ls[r], o);
      int row = i0 + rg * 16 + qd * 4 + r;
      float* orow = out + ((size_t)b * NS + row) * ND;
      if (ls[r] > 0.f) {
        float inv = 1.f / ls[r];
        #pragma unroll
        for (int gx = 0; gx < 4; ++gx) orow[gx * 16 + ln] = od[gx][r] * inv;
      } else {  // all-invalid row: reference softmax uniform over all j
        #pragma unroll
        for (int gx = 0; gx < 4; ++gx) orow[gx * 16 + ln] = vmean[b * ND + gx * 16 + ln];
      }
    }
  }
}

extern "C" void kernel_launch(void* const* d_in, const int* in_sizes, int n_in,
                              void* d_out, int out_size, void* d_ws, size_t ws_size,
                              hipStream_t stream) {
  (void)in_sizes; (void)n_in; (void)out_size; (void)ws_size;
  const float* x = (const float*)d_in[0];
  const int* mask = (const int*)d_in[1];
  const float* Wq = (const float*)d_in[2];
  const float* bq = (const float*)d_in[3];
  const float* Wk = (const float*)d_in[4];
  const float* bk = (const float*)d_in[5];
  const float* Wv = (const float*)d_in[6];
  const float* bv = (const float*)d_in[7];
  float* out = (float*)d_out;

  char* ws = (char*)d_ws;
  u16* Wcat3 = (u16*)ws;                  // 384 KB
  float* bcat = (float*)(ws + 393216);    // 768 B
  float* vmean = (float*)(ws + 394240);   // 2 KB
  u16* qb = (u16*)(ws + (1u << 20));      // 2 MB bf16 [b][s][d], pre-scaled by 1/8
  u16* kbf2 = (u16*)(ws + (3u << 20));    // 2 MB bf16 [b][s][d] swizzled
  u16* vtb2 = (u16*)(ws + (5u << 20));    // 2 MB bf16 [b][d][s] swizzled

  hipLaunchKernelGGL(k0_prep, dim3(96), dim3(256), 0, stream,
                     Wq, bq, Wk, bk, Wv, bv, Wcat3, bcat, vmean);
  hipLaunchKernelGGL(k1_qkv, dim3(512), dim3(512), 0, stream,
                     x, Wcat3, bcat, qb, kbf2, vtb2, vmean);
  hipLaunchKernelGGL(k3_attn, dim3(512), dim3(512), 0, stream,
                     qb, kbf2, vtb2, mask, vmean, out);
}